// Round 6
// baseline (369.916 us; speedup 1.0000x reference)
//
#include <hip/hip_runtime.h>
#include <hip/hip_bf16.h>
#include <cstdint>
#include <cstddef>

#define D_MODEL 1024
#define D_FF    4096
#define NTOK    4096   // B*S
#define SEQ     2048
#define NH      16
#define DK      64
#define LDQ     3072   // QKV fused row stride

typedef __bf16 bf16;
typedef __bf16 bf16_8 __attribute__((ext_vector_type(8)));
typedef __bf16 bf16_4 __attribute__((ext_vector_type(4)));
typedef float  f32_4  __attribute__((ext_vector_type(4)));
typedef float  f32_16 __attribute__((ext_vector_type(16)));

__device__ __forceinline__ void async_copy16(const bf16* g, bf16* l) {
    __builtin_amdgcn_global_load_lds((const __attribute__((address_space(1))) void*)g,
                                     (__attribute__((address_space(3))) void*)l,
                                     16, 0, 0);
}

// ---------------- fused cast fp32 -> bf16, all tensors in one dispatch -------
__global__ __launch_bounds__(256)
void cast_all(const float* __restrict__ x,  const float* __restrict__ Wq,
              const float* __restrict__ Wk, const float* __restrict__ Wv,
              const float* __restrict__ Wo, const float* __restrict__ W1,
              const float* __restrict__ W2,
              bf16* __restrict__ xb, bf16* __restrict__ Wqkvb,
              bf16* __restrict__ Wob, bf16* __restrict__ W1b,
              bf16* __restrict__ W2b) {
    const int blk = blockIdx.x;
    const float* s; bf16* d; int off;
    if (blk < 4096)       { s = x;  d = xb;              off = blk; }
    else if (blk < 5120)  { s = Wq; d = Wqkvb;           off = blk - 4096; }
    else if (blk < 6144)  { s = Wk; d = Wqkvb + 1048576; off = blk - 5120; }
    else if (blk < 7168)  { s = Wv; d = Wqkvb + 2097152; off = blk - 6144; }
    else if (blk < 8192)  { s = Wo; d = Wob;             off = blk - 7168; }
    else if (blk < 12288) { s = W1; d = W1b;             off = blk - 8192; }
    else                  { s = W2; d = W2b;             off = blk - 12288; }
    const int i = off * 1024 + threadIdx.x * 4;
    float4 v = *(const float4*)(s + i);
    bf16_4 o;
    o[0] = (bf16)v.x; o[1] = (bf16)v.y; o[2] = (bf16)v.z; o[3] = (bf16)v.w;
    *(bf16_4*)(d + i) = o;
}

// ---------------- BT-GEMM: C[M,N] = A[M,K] @ B[N,K]^T ----------------
// 128x128 tile, BK=32, 256 threads (4 waves 2x2). LDS granule-XOR swizzle.
// grid.z = split-K: part z covers K range [z*kLen, (z+1)*kLen), writes
// C0 + z*cstride. EPI: 0 = bf16 out, 2 = exact-GELU + bf16 out.
template <int EPI>
__global__ __launch_bounds__(256, 2)
void gemm_bt(const bf16* __restrict__ A, const bf16* __restrict__ B,
             bf16* __restrict__ C0, size_t cstride,
             int M, int N, int ldk, int kLen) {
    __shared__ bf16 As[128 * 32];
    __shared__ bf16 Bs[128 * 32];
    const int tid  = threadIdx.x;
    const int wave = tid >> 6, lane = tid & 63;
    const int quad = lane >> 4, l15 = lane & 15;
    const int wm = wave >> 1, wn = wave & 1;
    const int bm = blockIdx.x, bn = blockIdx.y, z = blockIdx.z;

    const bf16* A0 = A + (size_t)bm * 128 * ldk + (size_t)z * kLen;
    const bf16* B0 = B + (size_t)bn * 128 * ldk + (size_t)z * kLen;

    f32_4 acc[4][4];
#pragma unroll
    for (int i = 0; i < 4; i++)
#pragma unroll
        for (int j = 0; j < 4; j++) acc[i][j] = (f32_4){0.f, 0.f, 0.f, 0.f};

    const int ra = tid >> 2;                       // staging row 0..63
    const int gl = (tid & 3) ^ ((ra >> 1) & 3);    // logical granule for phys slot
    const int ca = gl * 8;                         // source col (elements)
    const int sx = (l15 >> 1) & 3;                 // fragment-read swizzle key

    for (int k0 = 0; k0 < kLen; k0 += 32) {
#pragma unroll
        for (int c = 0; c < 2; c++)
            async_copy16(&A0[(size_t)(c * 64 + ra) * ldk + k0 + ca],
                         &As[c * 2048 + wave * 512]);
#pragma unroll
        for (int c = 0; c < 2; c++)
            async_copy16(&B0[(size_t)(c * 64 + ra) * ldk + k0 + ca],
                         &Bs[c * 2048 + wave * 512]);
        __syncthreads();

        bf16_8 af[4], bfr[4];
#pragma unroll
        for (int mi = 0; mi < 4; mi++)
            af[mi] = *(const bf16_8*)&As[(wm * 64 + mi * 16 + l15) * 32 + ((quad ^ sx) * 8)];
#pragma unroll
        for (int ni = 0; ni < 4; ni++)
            bfr[ni] = *(const bf16_8*)&Bs[(wn * 64 + ni * 16 + l15) * 32 + ((quad ^ sx) * 8)];
#pragma unroll
        for (int mi = 0; mi < 4; mi++)
#pragma unroll
            for (int ni = 0; ni < 4; ni++)
                acc[mi][ni] = __builtin_amdgcn_mfma_f32_16x16x32_bf16(
                    af[mi], bfr[ni], acc[mi][ni], 0, 0, 0);
        __syncthreads();
    }

    bf16* C = C0 + (size_t)z * cstride;
    const int row0 = bm * 128 + wm * 64 + quad * 4;
    const int col0 = bn * 128 + wn * 64 + l15;
#pragma unroll
    for (int mi = 0; mi < 4; mi++) {
#pragma unroll
        for (int ni = 0; ni < 4; ni++) {
#pragma unroll
            for (int r = 0; r < 4; r++) {
                int row = row0 + mi * 16 + r;
                int col = col0 + ni * 16;
                size_t idx = (size_t)row * N + col;
                float v = acc[mi][ni][r];
                if (EPI == 0) {
                    C[idx] = (bf16)v;
                } else {
                    float g = 0.5f * v * (1.0f + erff(v * 0.70710678118654752f));
                    C[idx] = (bf16)g;
                }
            }
        }
    }
}

// ---------------- V transpose: QKV[:,2048+c] -> Vt[b][c][s] ----------------
__global__ __launch_bounds__(256)
void transpose_v(const bf16* __restrict__ QKV, bf16* __restrict__ Vt) {
    __shared__ bf16 T[64 * 72];
    const int tb = blockIdx.x;   // token tile (64 tokens)
    const int cb = blockIdx.y;   // channel tile (64 channels)
    const int tid = threadIdx.x;
    const int r = tid >> 3, g = tid & 7;
#pragma unroll
    for (int c = 0; c < 2; ++c) {
        int row = c * 32 + r;
        bf16_8 v = *(const bf16_8*)&QKV[(size_t)(tb * 64 + row) * LDQ + 2048 + cb * 64 + g * 8];
        *(bf16_8*)&T[row * 72 + g * 8] = v;
    }
    __syncthreads();
    const int b  = (tb * 64) >> 11;
    const int s0 = (tb * 64) & 2047;
#pragma unroll
    for (int c = 0; c < 2; ++c) {
        int ch = c * 32 + r;
        bf16_8 v;
#pragma unroll
        for (int j = 0; j < 8; ++j) v[j] = T[(g * 8 + j) * 72 + ch];
        *(bf16_8*)&Vt[(size_t)(b * 1024 + cb * 64 + ch) * SEQ + s0 + g * 8] = v;
    }
}

// ---------------- flash attention v5: 32x32x16 MFMA -------------------------
// Block: 64 q of one (b,h); grid 1024. Waves: qh = wave>>1 (q-half of 32),
// kh = wave&1 (key-half). Rounds stage 128 keys (K[128][64], V^T[64][128] in
// LDS, XOR-granule swizzled). S^T = K.Q^T via 32x32x16 (each lane's 16 C-regs
// = one q column). Fixed-shift softmax p = exp(s/8 - 8) (exact, shift cancels;
// fully key-parallel so waves split keys with a final pair-reduce).
// P C-layout -> PV B-operand via lane^32 register exchange (no LDS).
__global__ __launch_bounds__(256)
void attn5(const bf16* __restrict__ QKV, const bf16* __restrict__ Vt,
           bf16* __restrict__ O) {
    __shared__ __align__(16) bf16 SM[128 * 64 + 64 * 128];  // Ks | Vs, 32 KB
    __shared__ float Lsh[4][32];
    bf16* Ks = SM;             // [key 128][d 64], 8 granules/row, swz g^(row&7)
    bf16* Vs = SM + 128 * 64;  // [d 64][key 128], 16 granules/row, swz g^((row&7)<<1)

    const int tid  = threadIdx.x;
    const int wave = tid >> 6, lane = tid & 63;
    const int ln31 = lane & 31, hi = lane >> 5;
    const int qh = wave >> 1, kh = wave & 1;
    const int qb = blockIdx.x & 31;
    const int h  = (blockIdx.x >> 5) & 15;
    const int b  = blockIdx.x >> 9;

    const bf16* Qg = QKV + (size_t)(b * SEQ) * LDQ + h * 64;
    const bf16* Kg = QKV + (size_t)(b * SEQ) * LDQ + 1024 + h * 64;
    const bf16* Vg = Vt + (size_t)(b * 1024 + h * 64) * SEQ;

    // Q B-frags: B[k=d][n=q]: n = ln31, k = c*16 + hi*8 + j
    const int q0 = qb * 64 + qh * 32;
    bf16_8 qf[4];
#pragma unroll
    for (int c = 0; c < 4; c++)
        qf[c] = *(const bf16_8*)&Qg[(size_t)(q0 + ln31) * LDQ + c * 16 + hi * 8];

    f32_16 o0, o1;
#pragma unroll
    for (int r = 0; r < 16; r++) { o0[r] = 0.f; o1[r] = 0.f; }
    float l_lane = 0.f;

    const int krow_s = wave * 8 + (lane >> 3);   // K staging row-in-32
    const int kg_s   = lane & 7;
    const int vrow_s = wave * 4 + (lane >> 4);   // V staging row-in-16
    const int vg_s   = lane & 15;

    for (int t = 0; t < SEQ / 128; ++t) {
        const int k0 = t * 128;
        __syncthreads();
#pragma unroll
        for (int i = 0; i < 4; ++i) {
            int r = i * 32 + krow_s;
            async_copy16(&Kg[(size_t)(k0 + r) * LDQ + ((kg_s ^ (r & 7)) * 8)],
                         &Ks[(i * 32 + wave * 8) * 64]);
        }
#pragma unroll
        for (int i = 0; i < 4; ++i) {
            int r = i * 16 + vrow_s;
            async_copy16(&Vg[(size_t)r * SEQ + k0 + ((vg_s ^ ((r & 7) << 1)) * 8)],
                         &Vs[(i * 16 + wave * 4) * 128]);
        }
        __syncthreads();

        // ---- S^T = K.Q^T over this wave's 64 keys (2 tiles of 32) ----
        float p[2][16];
#pragma unroll
        for (int kt = 0; kt < 2; kt++) {
            const int krow = kh * 64 + kt * 32 + ln31;
            f32_16 acc;
#pragma unroll
            for (int r = 0; r < 16; r++) acc[r] = 0.f;
#pragma unroll
            for (int c = 0; c < 4; c++) {
                bf16_8 kf = *(const bf16_8*)&Ks[krow * 64 + (((2 * c + hi) ^ (krow & 7)) * 8)];
                acc = __builtin_amdgcn_mfma_f32_32x32x16_bf16(kf, qf[c], acc, 0, 0, 0);
            }
            // p = exp2(s * log2e/8 - 8*log2e)  (exact softmax numerator)
#pragma unroll
            for (int r = 0; r < 16; r++) {
                float pp = exp2f(fmaf(acc[r], 0.18033688011112042f,
                                      -11.541560327111707f));
                l_lane += pp;
                p[kt][r] = pp;
            }
        }

        // ---- P^T B-frags via lane^32 exchange (C rows: (r&3)+8(r>>2)+4hi) ----
        bf16_8 pfrag[4];
#pragma unroll
        for (int kc = 0; kc < 4; kc++) {
            const float* pp = p[kc >> 1] + 8 * (kc & 1);
            bf16_8 f;
#pragma unroll
            for (int j = 0; j < 4; j++) {
                float t0 = hi ? pp[j] : pp[j + 4];
                float rc = __shfl_xor(t0, 32);
                f[j]     = (bf16)(hi ? rc : pp[j]);
                f[4 + j] = (bf16)(hi ? pp[j + 4] : rc);
            }
            pfrag[kc] = f;
        }

        // ---- O^T += V^T.P^T  (A = V^T rows d, k = this wave's keys) ----
#pragma unroll
        for (int kc = 0; kc < 4; kc++) {
            const int g = kh * 8 + kc * 2 + hi;
            bf16_8 vf0 = *(const bf16_8*)&Vs[ln31 * 128 + ((g ^ ((ln31 & 7) << 1)) * 8)];
            o0 = __builtin_amdgcn_mfma_f32_32x32x16_bf16(vf0, pfrag[kc], o0, 0, 0, 0);
            const int vr1 = 32 + ln31;
            bf16_8 vf1 = *(const bf16_8*)&Vs[vr1 * 128 + ((g ^ ((vr1 & 7) << 1)) * 8)];
            o1 = __builtin_amdgcn_mfma_f32_32x32x16_bf16(vf1, pfrag[kc], o1, 0, 0, 0);
        }
    }

    // per-q denominator over this wave's keys (q = ln31 lives in lane & lane+32)
    l_lane += __shfl_xor(l_lane, 32);

    // ---- cross-wave (key-half) reduce + store ----
    __syncthreads();
    float* Osh = (float*)SM;  // 8192 floats
    if (kh == 1) {
        float* pub = Osh + qh * 2048;  // [reg 32][lane 64]
#pragma unroll
        for (int r = 0; r < 16; r++) {
            pub[r * 64 + lane]         = o0[r];
            pub[(16 + r) * 64 + lane]  = o1[r];
        }
    }
    if (hi == 0) Lsh[wave][ln31] = l_lane;
    __syncthreads();
    if (kh == 0) {
        const float* pub = Osh + qh * 2048;
        float L = Lsh[wave][ln31] + Lsh[wave + 1][ln31];
        float rl = 1.0f / L;
        bf16* ob = (bf16*)(Osh + 4096 + qh * 1024);  // [q 32][d 64] swizzled
#pragma unroll
        for (int dt = 0; dt < 2; dt++)
#pragma unroll
            for (int g = 0; g < 4; g++) {
                bf16_4 w;
#pragma unroll
                for (int jj = 0; jj < 4; jj++) {
                    int r = g * 4 + jj;
                    float own = dt ? o1[r] : o0[r];
                    w[jj] = (bf16)((own + pub[(dt * 16 + r) * 64 + lane]) * rl);
                }
                *(bf16_4*)&ob[ln31 * 64 + (((dt * 4 + g) ^ (ln31 & 7)) * 8) + hi * 4] = w;
            }
#pragma unroll
        for (int pass = 0; pass < 4; pass++) {
            int qr = pass * 8 + (lane >> 3);
            int lg = lane & 7;
            bf16_8 ov = *(const bf16_8*)&ob[qr * 64 + ((lg ^ (qr & 7)) * 8)];
            size_t tok = (size_t)b * SEQ + qb * 64 + qh * 32 + qr;
            *(bf16_8*)&O[tok * D_MODEL + h * 64 + lg * 8] = ov;
        }
    }
}

// ---------------- fused residual + 4-way partial add + LayerNorm -----------
template <bool A32, bool O32>
__global__ __launch_bounds__(256)
void ln_kernel(const void* __restrict__ av, const bf16* __restrict__ p0,
               const bf16* __restrict__ p1, const bf16* __restrict__ p2,
               const bf16* __restrict__ p3,
               const float* __restrict__ gamma, const float* __restrict__ beta,
               void* __restrict__ yv) {
    const int row = blockIdx.x;
    const int tid = threadIdx.x;
    const size_t off = (size_t)row * D_MODEL;
    float v[4];
    {
        bf16_4 a0 = *(const bf16_4*)(p0 + off + tid * 4);
        bf16_4 a1 = *(const bf16_4*)(p1 + off + tid * 4);
        bf16_4 a2 = *(const bf16_4*)(p2 + off + tid * 4);
        bf16_4 a3 = *(const bf16_4*)(p3 + off + tid * 4);
        if (A32) {
            float4 xa = *(const float4*)((const float*)av + off + tid * 4);
            v[0] = xa.x; v[1] = xa.y; v[2] = xa.z; v[3] = xa.w;
        } else {
            bf16_4 xa = *(const bf16_4*)((const bf16*)av + off + tid * 4);
#pragma unroll
            for (int i = 0; i < 4; i++) v[i] = (float)xa[i];
        }
#pragma unroll
        for (int i = 0; i < 4; i++)
            v[i] += ((float)a0[i] + (float)a1[i]) + ((float)a2[i] + (float)a3[i]);
    }
    float s = v[0] + v[1] + v[2] + v[3];
    float ss = v[0] * v[0] + v[1] * v[1] + v[2] * v[2] + v[3] * v[3];
#pragma unroll
    for (int m = 1; m < 64; m <<= 1) {
        s  += __shfl_xor(s, m);
        ss += __shfl_xor(ss, m);
    }
    __shared__ float red_s[4], red_q[4];
    int wave = tid >> 6, lane = tid & 63;
    if (lane == 0) { red_s[wave] = s; red_q[wave] = ss; }
    __syncthreads();
    s  = red_s[0] + red_s[1] + red_s[2] + red_s[3];
    ss = red_q[0] + red_q[1] + red_q[2] + red_q[3];
    float mu   = s * (1.f / D_MODEL);
    float var  = ss * (1.f / D_MODEL) - mu * mu;
    float rstd = rsqrtf(var + 1e-5f);
    float4 gg = *(const float4*)(gamma + tid * 4);
    float4 be = *(const float4*)(beta + tid * 4);
    float y0 = (v[0] - mu) * rstd * gg.x + be.x;
    float y1 = (v[1] - mu) * rstd * gg.y + be.y;
    float y2 = (v[2] - mu) * rstd * gg.z + be.z;
    float y3 = (v[3] - mu) * rstd * gg.w + be.w;
    if (O32) {
        *(float4*)((float*)yv + off + tid * 4) = make_float4(y0, y1, y2, y3);
    } else {
        bf16_4 o;
        o[0] = (bf16)y0; o[1] = (bf16)y1; o[2] = (bf16)y2; o[3] = (bf16)y3;
        *(bf16_4*)((bf16*)yv + off + tid * 4) = o;
    }
}

extern "C" void kernel_launch(void* const* d_in, const int* in_sizes, int n_in,
                              void* d_out, int out_size, void* d_ws, size_t ws_size,
                              hipStream_t stream) {
    (void)in_sizes; (void)n_in; (void)out_size; (void)ws_size;
    const float* x  = (const float*)d_in[0];
    const float* Wq = (const float*)d_in[1];
    const float* Wk = (const float*)d_in[2];
    const float* Wv = (const float*)d_in[3];
    const float* Wo = (const float*)d_in[4];
    const float* W1 = (const float*)d_in[5];
    const float* W2 = (const float*)d_in[6];
    const float* g1 = (const float*)d_in[7];
    const float* b1 = (const float*)d_in[8];
    const float* g2 = (const float*)d_in[9];
    const float* b2 = (const float*)d_in[10];

    char* ws = (char*)d_ws;
    // layout (bytes), total 96 MB. Timeline overlays:
    //   xb/aob [0,8M): cast x -> QKV input -> attn out -> dead after Wo
    //   ln1b   [0,8M): written by LN1 (after Wo), read by FF1 + LN2
    //   QKVb [8M,32M) + Vtb [32M,40M): dead after attn -> hb [8M,40M)
    bf16*  xb    = (bf16*)(ws + 0);          // 8 MB
    bf16*  aob   = xb;
    bf16*  ln1b  = (bf16*)(ws + 0);          // 8 MB (after aob dead)
    bf16*  QKVb  = (bf16*)(ws + 8388608);    // 24 MB [4096][3072]
    bf16*  Vtb   = (bf16*)(ws + 33554432);   // 8 MB  [b][1024][2048]
    bf16*  hb    = (bf16*)(ws + 8388608);    // 32 MB (overlay, post-attn)
    bf16*  Wqkvb = (bf16*)(ws + 41943040);   // 6 MB [3072][1024]
    bf16*  Wob   = (bf16*)(ws + 48234496);   // 2 MB
    bf16*  W1b   = (bf16*)(ws + 50331648);   // 8 MB
    bf16*  W2b   = (bf16*)(ws + 58720256);   // 8 MB
    bf16*  proj0 = (bf16*)(ws + 67108864);   // 4 x 8 MB split-K partials
    const size_t PSTRIDE = (size_t)NTOK * D_MODEL;  // 4M elements

    cast_all<<<dim3(16384), 256, 0, stream>>>(x, Wq, Wk, Wv, Wo, W1, W2,
                                              xb, Wqkvb, Wob, W1b, W2b);

    // fused QKV projection: [4096,1024] @ [3072,1024]^T
    gemm_bt<0><<<dim3(NTOK / 128, 3072 / 128, 1), 256, 0, stream>>>(
        xb, Wqkvb, QKVb, 0, NTOK, 3072, D_MODEL, D_MODEL);

    transpose_v<<<dim3(NTOK / 64, D_MODEL / 64), 256, 0, stream>>>(QKVb, Vtb);

    attn5<<<dim3(1024), 256, 0, stream>>>(QKVb, Vtb, aob);

    // Wo projection, split-K=4 (partials summed in LN1)
    gemm_bt<0><<<dim3(NTOK / 128, D_MODEL / 128, 4), 256, 0, stream>>>(
        aob, Wob, proj0, PSTRIDE, NTOK, D_MODEL, D_MODEL, 256);
    ln_kernel<true, false><<<NTOK, 256, 0, stream>>>(
        x, proj0, proj0 + PSTRIDE, proj0 + 2 * PSTRIDE, proj0 + 3 * PSTRIDE,
        g1, b1, ln1b);

    // FF1 + exact GELU
    gemm_bt<2><<<dim3(NTOK / 128, D_FF / 128, 1), 256, 0, stream>>>(
        ln1b, W1b, hb, 0, NTOK, D_FF, D_MODEL, D_MODEL);

    // FF2, split-K=4 (partials summed in LN2)
    gemm_bt<0><<<dim3(NTOK / 128, D_MODEL / 128, 4), 256, 0, stream>>>(
        hb, W2b, proj0, PSTRIDE, NTOK, D_MODEL, D_FF, 1024);
    ln_kernel<false, true><<<NTOK, 256, 0, stream>>>(
        ln1b, proj0, proj0 + PSTRIDE, proj0 + 2 * PSTRIDE, proj0 + 3 * PSTRIDE,
        g2, b2, d_out);
}

// Round 7
// 346.772 us; speedup vs baseline: 1.0667x; 1.0667x over previous
//
#include <hip/hip_runtime.h>
#include <hip/hip_bf16.h>
#include <cstdint>
#include <cstddef>

#define D_MODEL 1024
#define D_FF    4096
#define NTOK    4096   // B*S
#define SEQ     2048
#define NH      16
#define DK      64
#define LDQ     3072   // QKV fused row stride

typedef __bf16 bf16;
typedef __bf16 bf16_8 __attribute__((ext_vector_type(8)));
typedef __bf16 bf16_4 __attribute__((ext_vector_type(4)));
typedef float  f32_4  __attribute__((ext_vector_type(4)));

__device__ __forceinline__ void async_copy16(const bf16* g, bf16* l) {
    __builtin_amdgcn_global_load_lds((const __attribute__((address_space(1))) void*)g,
                                     (__attribute__((address_space(3))) void*)l,
                                     16, 0, 0);
}

// ---------------- fused cast fp32 -> bf16, all tensors in one dispatch -------
__global__ __launch_bounds__(256)
void cast_all(const float* __restrict__ x,  const float* __restrict__ Wq,
              const float* __restrict__ Wk, const float* __restrict__ Wv,
              const float* __restrict__ Wo, const float* __restrict__ W1,
              const float* __restrict__ W2,
              bf16* __restrict__ xb, bf16* __restrict__ Wqkvb,
              bf16* __restrict__ Wob, bf16* __restrict__ W1b,
              bf16* __restrict__ W2b) {
    const int blk = blockIdx.x;
    const float* s; bf16* d; int off;
    if (blk < 4096)       { s = x;  d = xb;              off = blk; }
    else if (blk < 5120)  { s = Wq; d = Wqkvb;           off = blk - 4096; }
    else if (blk < 6144)  { s = Wk; d = Wqkvb + 1048576; off = blk - 5120; }
    else if (blk < 7168)  { s = Wv; d = Wqkvb + 2097152; off = blk - 6144; }
    else if (blk < 8192)  { s = Wo; d = Wob;             off = blk - 7168; }
    else if (blk < 12288) { s = W1; d = W1b;             off = blk - 8192; }
    else                  { s = W2; d = W2b;             off = blk - 12288; }
    const int i = off * 1024 + threadIdx.x * 4;
    float4 v = *(const float4*)(s + i);
    bf16_4 o;
    o[0] = (bf16)v.x; o[1] = (bf16)v.y; o[2] = (bf16)v.z; o[3] = (bf16)v.w;
    *(bf16_4*)(d + i) = o;
}

// ---------------- BT-GEMM: C[M,N] = A[M,K] @ B[N,K]^T ----------------
// 128x128 tile, BK=32, 256 threads (4 waves 2x2). LDS granule-XOR swizzle.
// grid.z = split-K: part z covers [z*kLen, (z+1)*kLen), writes C0+z*cstride.
// EPI: 0 = bf16 out, 2 = exact-GELU + bf16 out,
//      3 = QKV mode: bn<16 -> normal store; bn>=16 (V third) -> transposed
//          store into Vt[b][ch][s] (fuses the V transpose into the epilogue).
template <int EPI>
__global__ __launch_bounds__(256, 2)
void gemm_bt(const bf16* __restrict__ A, const bf16* __restrict__ B,
             bf16* __restrict__ C0, size_t cstride, bf16* __restrict__ Vt,
             int M, int N, int ldk, int kLen) {
    __shared__ bf16 As[128 * 32];
    __shared__ bf16 Bs[128 * 32];
    const int tid  = threadIdx.x;
    const int wave = tid >> 6, lane = tid & 63;
    const int quad = lane >> 4, l15 = lane & 15;
    const int wm = wave >> 1, wn = wave & 1;
    const int bm = blockIdx.x, bn = blockIdx.y, z = blockIdx.z;

    const bf16* A0 = A + (size_t)bm * 128 * ldk + (size_t)z * kLen;
    const bf16* B0 = B + (size_t)bn * 128 * ldk + (size_t)z * kLen;

    f32_4 acc[4][4];
#pragma unroll
    for (int i = 0; i < 4; i++)
#pragma unroll
        for (int j = 0; j < 4; j++) acc[i][j] = (f32_4){0.f, 0.f, 0.f, 0.f};

    const int ra = tid >> 2;                       // staging row 0..63
    const int gl = (tid & 3) ^ ((ra >> 1) & 3);    // logical granule for phys slot
    const int ca = gl * 8;                         // source col (elements)
    const int sx = (l15 >> 1) & 3;                 // fragment-read swizzle key

    for (int k0 = 0; k0 < kLen; k0 += 32) {
#pragma unroll
        for (int c = 0; c < 2; c++)
            async_copy16(&A0[(size_t)(c * 64 + ra) * ldk + k0 + ca],
                         &As[c * 2048 + wave * 512]);
#pragma unroll
        for (int c = 0; c < 2; c++)
            async_copy16(&B0[(size_t)(c * 64 + ra) * ldk + k0 + ca],
                         &Bs[c * 2048 + wave * 512]);
        __syncthreads();

        bf16_8 af[4], bfr[4];
#pragma unroll
        for (int mi = 0; mi < 4; mi++)
            af[mi] = *(const bf16_8*)&As[(wm * 64 + mi * 16 + l15) * 32 + ((quad ^ sx) * 8)];
#pragma unroll
        for (int ni = 0; ni < 4; ni++)
            bfr[ni] = *(const bf16_8*)&Bs[(wn * 64 + ni * 16 + l15) * 32 + ((quad ^ sx) * 8)];
#pragma unroll
        for (int mi = 0; mi < 4; mi++)
#pragma unroll
            for (int ni = 0; ni < 4; ni++)
                acc[mi][ni] = __builtin_amdgcn_mfma_f32_16x16x32_bf16(
                    af[mi], bfr[ni], acc[mi][ni], 0, 0, 0);
        __syncthreads();
    }

    bf16* C = C0 + (size_t)z * cstride;
    const int row0 = bm * 128 + wm * 64 + quad * 4;
    const int col0 = bn * 128 + wn * 64 + l15;

    if (EPI == 3 && bn >= 16) {
        // V third: store transposed into Vt[b][ch][s]
        const int bvt  = bm >> 4;          // batch (128-row tiles never straddle)
#pragma unroll
        for (int mi = 0; mi < 4; mi++) {
            const int srow = (row0 + mi * 16) & 2047;
#pragma unroll
            for (int ni = 0; ni < 4; ni++) {
                const int ch = col0 + ni * 16 - 2048;
                bf16_4 w;
#pragma unroll
                for (int r = 0; r < 4; r++) w[r] = (bf16)acc[mi][ni][r];
                *(bf16_4*)&Vt[((size_t)(bvt * 1024 + ch)) * SEQ + srow] = w;
            }
        }
        return;
    }

#pragma unroll
    for (int mi = 0; mi < 4; mi++) {
#pragma unroll
        for (int ni = 0; ni < 4; ni++) {
#pragma unroll
            for (int r = 0; r < 4; r++) {
                int row = row0 + mi * 16 + r;
                int col = col0 + ni * 16;
                size_t idx = (size_t)row * N + col;
                float v = acc[mi][ni][r];
                if (EPI == 2) {
                    float g = 0.5f * v * (1.0f + erff(v * 0.70710678118654752f));
                    C[idx] = (bf16)g;
                } else {
                    C[idx] = (bf16)v;
                }
            }
        }
    }
}

// ---------------- flash attention: S^T orientation, fixed-shift softmax ----
// (round-4 attn3, measured 64 us) Block: 64 q of one (b,h), 4 waves x 16 q.
__global__ __launch_bounds__(256)
void attn3(const bf16* __restrict__ QKV, const bf16* __restrict__ Vt,
           bf16* __restrict__ O) {
    __shared__ bf16 Ks[64 * 64];     // [key][d], granule-8 XOR swizzle
    __shared__ bf16 Vs[64 * 64];     // [d][key], granule-8 XOR swizzle
    __shared__ bf16 Ps[4][16 * 80];  // per-wave [q][key]

    const int tid  = threadIdx.x;
    const int wave = tid >> 6, lane = tid & 63;
    const int quad = lane >> 4, l15 = lane & 15;
    const int qb = blockIdx.x & 31;
    const int h  = (blockIdx.x >> 5) & 15;
    const int b  = blockIdx.x >> 9;

    const bf16* Qg = QKV + (size_t)(b * SEQ) * LDQ + h * 64;
    const bf16* Kg = QKV + (size_t)(b * SEQ) * LDQ + 1024 + h * 64;
    const bf16* Vg = Vt + (size_t)(b * 1024 + h * 64) * SEQ;

    const int qrow = qb * 64 + wave * 16 + l15;
    const bf16_8 qf0 = *(const bf16_8*)&Qg[(size_t)qrow * LDQ + quad * 8];
    const bf16_8 qf1 = *(const bf16_8*)&Qg[(size_t)qrow * LDQ + 32 + quad * 8];

    const int srow = wave * 8 + (lane >> 3);  // staging row within half-tile
    const int sg   = lane & 7;                // phys granule this lane fills
    const int xl   = l15 & 7;                 // fragment swizzle key

    float l_lane = 0.f;
    f32_4 o_acc[4];
#pragma unroll
    for (int d = 0; d < 4; d++) o_acc[d] = (f32_4){0.f, 0.f, 0.f, 0.f};

    bf16* P = Ps[wave];

    for (int t = 0; t < SEQ / 64; ++t) {
        const int k0 = t * 64;
        __syncthreads();
#pragma unroll
        for (int c = 0; c < 2; ++c) {
            int r = c * 32 + srow;
            async_copy16(&Kg[(size_t)(k0 + r) * LDQ + ((sg ^ (r & 7)) * 8)],
                         &Ks[c * 2048 + wave * 512]);
            async_copy16(&Vg[(size_t)r * SEQ + k0 + ((sg ^ (r & 7)) * 8)],
                         &Vs[c * 2048 + wave * 512]);
        }
        __syncthreads();

        // ---- S^T = K.Q^T : s[ni] holds keys ni*16+quad*4+r for q=l15 ----
        f32_4 s[4];
#pragma unroll
        for (int ni = 0; ni < 4; ni++) {
            const bf16* kp = &Ks[(ni * 16 + l15) * 64];
            bf16_8 kb0 = *(const bf16_8*)&kp[(quad ^ xl) * 8];
            bf16_8 kb1 = *(const bf16_8*)&kp[((quad + 4) ^ xl) * 8];
            f32_4 z = (f32_4){0.f, 0.f, 0.f, 0.f};
            z = __builtin_amdgcn_mfma_f32_16x16x32_bf16(kb0, qf0, z, 0, 0, 0);
            s[ni] = __builtin_amdgcn_mfma_f32_16x16x32_bf16(kb1, qf1, z, 0, 0, 0);
        }

        // ---- fixed-shift softmax: p = exp2(s*log2e/8 - 8*log2e) ----
#pragma unroll
        for (int ni = 0; ni < 4; ni++) {
            bf16_4 pk;
#pragma unroll
            for (int r = 0; r < 4; r++) {
                float p = exp2f(fmaf(s[ni][r], 0.18033688011112042f,
                                     -11.541560327111707f));
                l_lane += p;
                pk[r] = (bf16)p;
            }
            int G = ni * 2 + (quad >> 1);
            *(bf16_4*)&P[l15 * 80 + ((G ^ xl) * 8) + ((quad & 1) * 4)] = pk;
        }
        bf16_8 pf0 = *(const bf16_8*)&P[l15 * 80 + ((quad ^ xl) * 8)];
        bf16_8 pf1 = *(const bf16_8*)&P[l15 * 80 + (((quad + 4) ^ xl) * 8)];

        // ---- O^T[d][q] += V^T.P^T ----
#pragma unroll
        for (int dt = 0; dt < 4; dt++) {
            const bf16* vp = &Vs[(dt * 16 + l15) * 64];
            bf16_8 vb0 = *(const bf16_8*)&vp[(quad ^ xl) * 8];
            bf16_8 vb1 = *(const bf16_8*)&vp[((quad + 4) ^ xl) * 8];
            o_acc[dt] = __builtin_amdgcn_mfma_f32_16x16x32_bf16(vb0, pf0, o_acc[dt], 0, 0, 0);
            o_acc[dt] = __builtin_amdgcn_mfma_f32_16x16x32_bf16(vb1, pf1, o_acc[dt], 0, 0, 0);
        }
    }

    l_lane += __shfl_xor(l_lane, 16);
    l_lane += __shfl_xor(l_lane, 32);
    const float rl = 1.0f / l_lane;

    // O^T -> LDS [q][d] -> coalesced b128 stores
#pragma unroll
    for (int dt = 0; dt < 4; dt++) {
        bf16_4 pk;
#pragma unroll
        for (int r = 0; r < 4; r++) pk[r] = (bf16)(o_acc[dt][r] * rl);
        int G = dt * 2 + (quad >> 1);
        *(bf16_4*)&P[l15 * 80 + ((G ^ xl) * 8) + ((quad & 1) * 4)] = pk;
    }
    const int q2 = lane >> 2, dc = lane & 3, x2 = q2 & 7;
    bf16_8 o0 = *(const bf16_8*)&P[q2 * 80 + (((dc * 2) ^ x2) * 8)];
    bf16_8 o1 = *(const bf16_8*)&P[q2 * 80 + (((dc * 2 + 1) ^ x2) * 8)];
    const size_t row = (size_t)b * SEQ + qb * 64 + wave * 16 + q2;
    *(bf16_8*)&O[row * D_MODEL + h * 64 + dc * 16] = o0;
    *(bf16_8*)&O[row * D_MODEL + h * 64 + dc * 16 + 8] = o1;
}

// ---------------- fused residual + 4-way partial add + LayerNorm -----------
template <bool A32, bool O32>
__global__ __launch_bounds__(256)
void ln_kernel(const void* __restrict__ av, const bf16* __restrict__ p0,
               const bf16* __restrict__ p1, const bf16* __restrict__ p2,
               const bf16* __restrict__ p3,
               const float* __restrict__ gamma, const float* __restrict__ beta,
               void* __restrict__ yv) {
    const int row = blockIdx.x;
    const int tid = threadIdx.x;
    const size_t off = (size_t)row * D_MODEL;
    float v[4];
    {
        bf16_4 a0 = *(const bf16_4*)(p0 + off + tid * 4);
        bf16_4 a1 = *(const bf16_4*)(p1 + off + tid * 4);
        bf16_4 a2 = *(const bf16_4*)(p2 + off + tid * 4);
        bf16_4 a3 = *(const bf16_4*)(p3 + off + tid * 4);
        if (A32) {
            float4 xa = *(const float4*)((const float*)av + off + tid * 4);
            v[0] = xa.x; v[1] = xa.y; v[2] = xa.z; v[3] = xa.w;
        } else {
            bf16_4 xa = *(const bf16_4*)((const bf16*)av + off + tid * 4);
#pragma unroll
            for (int i = 0; i < 4; i++) v[i] = (float)xa[i];
        }
#pragma unroll
        for (int i = 0; i < 4; i++)
            v[i] += ((float)a0[i] + (float)a1[i]) + ((float)a2[i] + (float)a3[i]);
    }
    float s = v[0] + v[1] + v[2] + v[3];
    float ss = v[0] * v[0] + v[1] * v[1] + v[2] * v[2] + v[3] * v[3];
#pragma unroll
    for (int m = 1; m < 64; m <<= 1) {
        s  += __shfl_xor(s, m);
        ss += __shfl_xor(ss, m);
    }
    __shared__ float red_s[4], red_q[4];
    int wave = tid >> 6, lane = tid & 63;
    if (lane == 0) { red_s[wave] = s; red_q[wave] = ss; }
    __syncthreads();
    s  = red_s[0] + red_s[1] + red_s[2] + red_s[3];
    ss = red_q[0] + red_q[1] + red_q[2] + red_q[3];
    float mu   = s * (1.f / D_MODEL);
    float var  = ss * (1.f / D_MODEL) - mu * mu;
    float rstd = rsqrtf(var + 1e-5f);
    float4 gg = *(const float4*)(gamma + tid * 4);
    float4 be = *(const float4*)(beta + tid * 4);
    float y0 = (v[0] - mu) * rstd * gg.x + be.x;
    float y1 = (v[1] - mu) * rstd * gg.y + be.y;
    float y2 = (v[2] - mu) * rstd * gg.z + be.z;
    float y3 = (v[3] - mu) * rstd * gg.w + be.w;
    if (O32) {
        *(float4*)((float*)yv + off + tid * 4) = make_float4(y0, y1, y2, y3);
    } else {
        bf16_4 o;
        o[0] = (bf16)y0; o[1] = (bf16)y1; o[2] = (bf16)y2; o[3] = (bf16)y3;
        *(bf16_4*)((bf16*)yv + off + tid * 4) = o;
    }
}

extern "C" void kernel_launch(void* const* d_in, const int* in_sizes, int n_in,
                              void* d_out, int out_size, void* d_ws, size_t ws_size,
                              hipStream_t stream) {
    (void)in_sizes; (void)n_in; (void)out_size; (void)ws_size;
    const float* x  = (const float*)d_in[0];
    const float* Wq = (const float*)d_in[1];
    const float* Wk = (const float*)d_in[2];
    const float* Wv = (const float*)d_in[3];
    const float* Wo = (const float*)d_in[4];
    const float* W1 = (const float*)d_in[5];
    const float* W2 = (const float*)d_in[6];
    const float* g1 = (const float*)d_in[7];
    const float* b1 = (const float*)d_in[8];
    const float* g2 = (const float*)d_in[9];
    const float* b2 = (const float*)d_in[10];

    char* ws = (char*)d_ws;
    // layout (bytes), total 96 MB. Timeline overlays:
    //   xb/aob [0,8M): cast x -> QKV input -> attn out -> dead after Wo
    //   ln1b   [0,8M): written by LN1 (after Wo), read by FF1 + LN2
    //   QKVb [8M,32M) + Vtb [32M,40M): dead after attn -> hb [8M,40M)
    bf16*  xb    = (bf16*)(ws + 0);          // 8 MB
    bf16*  aob   = xb;
    bf16*  ln1b  = (bf16*)(ws + 0);          // 8 MB (after aob dead)
    bf16*  QKVb  = (bf16*)(ws + 8388608);    // 24 MB [4096][3072] (V third unused)
    bf16*  Vtb   = (bf16*)(ws + 33554432);   // 8 MB  [b][1024][2048]
    bf16*  hb    = (bf16*)(ws + 8388608);    // 32 MB (overlay, post-attn)
    bf16*  Wqkvb = (bf16*)(ws + 41943040);   // 6 MB [3072][1024]
    bf16*  Wob   = (bf16*)(ws + 48234496);   // 2 MB
    bf16*  W1b   = (bf16*)(ws + 50331648);   // 8 MB
    bf16*  W2b   = (bf16*)(ws + 58720256);   // 8 MB
    bf16*  proj0 = (bf16*)(ws + 67108864);   // 4 x 8 MB split-K partials
    const size_t PSTRIDE = (size_t)NTOK * D_MODEL;  // 4M elements

    cast_all<<<dim3(16384), 256, 0, stream>>>(x, Wq, Wk, Wv, Wo, W1, W2,
                                              xb, Wqkvb, Wob, W1b, W2b);

    // fused QKV projection; V third stored transposed into Vtb (EPI=3)
    gemm_bt<3><<<dim3(NTOK / 128, 3072 / 128, 1), 256, 0, stream>>>(
        xb, Wqkvb, QKVb, 0, Vtb, NTOK, 3072, D_MODEL, D_MODEL);

    attn3<<<dim3(1024), 256, 0, stream>>>(QKVb, Vtb, aob);

    // Wo projection, split-K=4 (partials summed in LN1)
    gemm_bt<0><<<dim3(NTOK / 128, D_MODEL / 128, 4), 256, 0, stream>>>(
        aob, Wob, proj0, PSTRIDE, nullptr, NTOK, D_MODEL, D_MODEL, 256);
    ln_kernel<true, false><<<NTOK, 256, 0, stream>>>(
        x, proj0, proj0 + PSTRIDE, proj0 + 2 * PSTRIDE, proj0 + 3 * PSTRIDE,
        g1, b1, ln1b);

    // FF1 + exact GELU
    gemm_bt<2><<<dim3(NTOK / 128, D_FF / 128, 1), 256, 0, stream>>>(
        ln1b, W1b, hb, 0, nullptr, NTOK, D_FF, D_MODEL, D_MODEL);

    // FF2, split-K=4 (partials summed in LN2)
    gemm_bt<0><<<dim3(NTOK / 128, D_MODEL / 128, 4), 256, 0, stream>>>(
        hb, W2b, proj0, PSTRIDE, nullptr, NTOK, D_MODEL, D_FF, 1024);
    ln_kernel<false, true><<<NTOK, 256, 0, stream>>>(
        ln1b, proj0, proj0 + PSTRIDE, proj0 + 2 * PSTRIDE, proj0 + 3 * PSTRIDE,
        g2, b2, d_out);
}

// Round 8
// 313.876 us; speedup vs baseline: 1.1785x; 1.1048x over previous
//
#include <hip/hip_runtime.h>
#include <hip/hip_bf16.h>
#include <cstdint>
#include <cstddef>

#define D_MODEL 1024
#define D_FF    4096
#define NTOK    4096   // B*S
#define SEQ     2048
#define NH      16
#define DK      64
#define LDQ     3072   // QKV fused row stride

typedef __bf16 bf16;
typedef __bf16 bf16_8 __attribute__((ext_vector_type(8)));
typedef __bf16 bf16_4 __attribute__((ext_vector_type(4)));
typedef float  f32_4  __attribute__((ext_vector_type(4)));

__device__ __forceinline__ void async_copy16(const bf16* g, bf16* l) {
    __builtin_amdgcn_global_load_lds((const __attribute__((address_space(1))) void*)g,
                                     (__attribute__((address_space(3))) void*)l,
                                     16, 0, 0);
}

// ---------------- fused cast fp32 -> bf16, all tensors in one dispatch -------
__global__ __launch_bounds__(256)
void cast_all(const float* __restrict__ x,  const float* __restrict__ Wq,
              const float* __restrict__ Wk, const float* __restrict__ Wv,
              const float* __restrict__ Wo, const float* __restrict__ W1,
              const float* __restrict__ W2,
              bf16* __restrict__ xb, bf16* __restrict__ Wqkvb,
              bf16* __restrict__ Wob, bf16* __restrict__ W1b,
              bf16* __restrict__ W2b) {
    const int blk = blockIdx.x;
    const float* s; bf16* d; int off;
    if (blk < 4096)       { s = x;  d = xb;              off = blk; }
    else if (blk < 5120)  { s = Wq; d = Wqkvb;           off = blk - 4096; }
    else if (blk < 6144)  { s = Wk; d = Wqkvb + 1048576; off = blk - 5120; }
    else if (blk < 7168)  { s = Wv; d = Wqkvb + 2097152; off = blk - 6144; }
    else if (blk < 8192)  { s = Wo; d = Wob;             off = blk - 7168; }
    else if (blk < 12288) { s = W1; d = W1b;             off = blk - 8192; }
    else                  { s = W2; d = W2b;             off = blk - 12288; }
    const int i = off * 1024 + threadIdx.x * 4;
    float4 v = *(const float4*)(s + i);
    bf16_4 o;
    o[0] = (bf16)v.x; o[1] = (bf16)v.y; o[2] = (bf16)v.z; o[3] = (bf16)v.w;
    *(bf16_4*)(d + i) = o;
}

// ---------------- BT-GEMM: C[M,N] = A[M,K] @ B[N,K]^T ----------------
// 128x128 tile, BK=64 (32 MFMAs per barrier - halves the vmcnt(0) barrier
// drains vs BK=32), 256 threads (4 waves 2x2). LDS 2x16KB. Granule swizzle:
// phys_granule = logical ^ (row&7) -> conflict-free ds_read_b128.
// grid.z = split-K: part z covers [z*kLen, (z+1)*kLen), writes C0+z*cstride.
// EPI: 0 = bf16 out, 2 = exact-GELU + bf16 out,
//      3 = QKV mode: bn>=16 (V third) stores transposed into Vt[b][ch][s].
template <int EPI>
__global__ __launch_bounds__(256, 2)
void gemm_bt(const bf16* __restrict__ A, const bf16* __restrict__ B,
             bf16* __restrict__ C0, size_t cstride, bf16* __restrict__ Vt,
             int M, int N, int ldk, int kLen) {
    __shared__ bf16 As[128 * 64];
    __shared__ bf16 Bs[128 * 64];
    const int tid  = threadIdx.x;
    const int wave = tid >> 6, lane = tid & 63;
    const int quad = lane >> 4, l15 = lane & 15;
    const int wm = wave >> 1, wn = wave & 1;
    const int bm = blockIdx.x, bn = blockIdx.y, z = blockIdx.z;

    const bf16* A0 = A + (size_t)bm * 128 * ldk + (size_t)z * kLen;
    const bf16* B0 = B + (size_t)bn * 128 * ldk + (size_t)z * kLen;

    f32_4 acc[4][4];
#pragma unroll
    for (int i = 0; i < 4; i++)
#pragma unroll
        for (int j = 0; j < 4; j++) acc[i][j] = (f32_4){0.f, 0.f, 0.f, 0.f};

    const int srow8 = lane >> 3;                 // row-in-8 this lane fills
    const int slog  = (lane & 7) ^ srow8;        // logical granule (phys=lane&7)
    const int rx    = l15 & 7;                   // fragment-read swizzle key

    for (int k0 = 0; k0 < kLen; k0 += 64) {
#pragma unroll
        for (int c = 0; c < 4; c++) {
            int row = c * 32 + wave * 8 + srow8;
            async_copy16(&A0[(size_t)row * ldk + k0 + slog * 8],
                         &As[(c * 32 + wave * 8) * 64]);
        }
#pragma unroll
        for (int c = 0; c < 4; c++) {
            int row = c * 32 + wave * 8 + srow8;
            async_copy16(&B0[(size_t)row * ldk + k0 + slog * 8],
                         &Bs[(c * 32 + wave * 8) * 64]);
        }
        __syncthreads();

#pragma unroll
        for (int kh = 0; kh < 2; kh++) {
            bf16_8 af[4], bfr[4];
#pragma unroll
            for (int mi = 0; mi < 4; mi++)
                af[mi] = *(const bf16_8*)&As[(wm * 64 + mi * 16 + l15) * 64 +
                                             (((kh * 4 + quad) ^ rx) * 8)];
#pragma unroll
            for (int ni = 0; ni < 4; ni++)
                bfr[ni] = *(const bf16_8*)&Bs[(wn * 64 + ni * 16 + l15) * 64 +
                                              (((kh * 4 + quad) ^ rx) * 8)];
#pragma unroll
            for (int mi = 0; mi < 4; mi++)
#pragma unroll
                for (int ni = 0; ni < 4; ni++)
                    acc[mi][ni] = __builtin_amdgcn_mfma_f32_16x16x32_bf16(
                        af[mi], bfr[ni], acc[mi][ni], 0, 0, 0);
        }
        __syncthreads();
    }

    bf16* C = C0 + (size_t)z * cstride;
    const int row0 = bm * 128 + wm * 64 + quad * 4;
    const int col0 = bn * 128 + wn * 64 + l15;

    if (EPI == 3 && bn >= 16) {
        // V third: store transposed into Vt[b][ch][s]
        const int bvt = bm >> 4;           // batch (128-row tiles never straddle)
#pragma unroll
        for (int mi = 0; mi < 4; mi++) {
            const int srow = (row0 + mi * 16) & 2047;
#pragma unroll
            for (int ni = 0; ni < 4; ni++) {
                const int ch = col0 + ni * 16 - 2048;
                bf16_4 w;
#pragma unroll
                for (int r = 0; r < 4; r++) w[r] = (bf16)acc[mi][ni][r];
                *(bf16_4*)&Vt[((size_t)(bvt * 1024 + ch)) * SEQ + srow] = w;
            }
        }
        return;
    }

#pragma unroll
    for (int mi = 0; mi < 4; mi++) {
#pragma unroll
        for (int ni = 0; ni < 4; ni++) {
#pragma unroll
            for (int r = 0; r < 4; r++) {
                int row = row0 + mi * 16 + r;
                int col = col0 + ni * 16;
                size_t idx = (size_t)row * N + col;
                float v = acc[mi][ni][r];
                if (EPI == 2) {
                    float g = 0.5f * v * (1.0f + erff(v * 0.70710678118654752f));
                    C[idx] = (bf16)g;
                } else {
                    C[idx] = (bf16)v;
                }
            }
        }
    }
}

// ---------------- flash attention: S^T orientation, fixed-shift softmax ----
// (round-4 attn3 verbatim, measured 64 us) Block: 64 q of one (b,h).
__global__ __launch_bounds__(256)
void attn3(const bf16* __restrict__ QKV, const bf16* __restrict__ Vt,
           bf16* __restrict__ O) {
    __shared__ bf16 Ks[64 * 64];     // [key][d], granule-8 XOR swizzle
    __shared__ bf16 Vs[64 * 64];     // [d][key], granule-8 XOR swizzle
    __shared__ bf16 Ps[4][16 * 80];  // per-wave [q][key]

    const int tid  = threadIdx.x;
    const int wave = tid >> 6, lane = tid & 63;
    const int quad = lane >> 4, l15 = lane & 15;
    const int qb = blockIdx.x & 31;
    const int h  = (blockIdx.x >> 5) & 15;
    const int b  = blockIdx.x >> 9;

    const bf16* Qg = QKV + (size_t)(b * SEQ) * LDQ + h * 64;
    const bf16* Kg = QKV + (size_t)(b * SEQ) * LDQ + 1024 + h * 64;
    const bf16* Vg = Vt + (size_t)(b * 1024 + h * 64) * SEQ;

    const int qrow = qb * 64 + wave * 16 + l15;
    const bf16_8 qf0 = *(const bf16_8*)&Qg[(size_t)qrow * LDQ + quad * 8];
    const bf16_8 qf1 = *(const bf16_8*)&Qg[(size_t)qrow * LDQ + 32 + quad * 8];

    const int srow = wave * 8 + (lane >> 3);  // staging row within half-tile
    const int sg   = lane & 7;                // phys granule this lane fills
    const int xl   = l15 & 7;                 // fragment swizzle key

    float l_lane = 0.f;
    f32_4 o_acc[4];
#pragma unroll
    for (int d = 0; d < 4; d++) o_acc[d] = (f32_4){0.f, 0.f, 0.f, 0.f};

    bf16* P = Ps[wave];

    for (int t = 0; t < SEQ / 64; ++t) {
        const int k0 = t * 64;
        __syncthreads();
#pragma unroll
        for (int c = 0; c < 2; ++c) {
            int r = c * 32 + srow;
            async_copy16(&Kg[(size_t)(k0 + r) * LDQ + ((sg ^ (r & 7)) * 8)],
                         &Ks[c * 2048 + wave * 512]);
            async_copy16(&Vg[(size_t)r * SEQ + k0 + ((sg ^ (r & 7)) * 8)],
                         &Vs[c * 2048 + wave * 512]);
        }
        __syncthreads();

        // ---- S^T = K.Q^T : s[ni] holds keys ni*16+quad*4+r for q=l15 ----
        f32_4 s[4];
#pragma unroll
        for (int ni = 0; ni < 4; ni++) {
            const bf16* kp = &Ks[(ni * 16 + l15) * 64];
            bf16_8 kb0 = *(const bf16_8*)&kp[(quad ^ xl) * 8];
            bf16_8 kb1 = *(const bf16_8*)&kp[((quad + 4) ^ xl) * 8];
            f32_4 z = (f32_4){0.f, 0.f, 0.f, 0.f};
            z = __builtin_amdgcn_mfma_f32_16x16x32_bf16(kb0, qf0, z, 0, 0, 0);
            s[ni] = __builtin_amdgcn_mfma_f32_16x16x32_bf16(kb1, qf1, z, 0, 0, 0);
        }

        // ---- fixed-shift softmax: p = exp(s/8 - 8) via fast __expf ----
#pragma unroll
        for (int ni = 0; ni < 4; ni++) {
            bf16_4 pk;
#pragma unroll
            for (int r = 0; r < 4; r++) {
                float p = __expf(fmaf(s[ni][r], 0.125f, -8.0f));
                l_lane += p;
                pk[r] = (bf16)p;
            }
            int G = ni * 2 + (quad >> 1);
            *(bf16_4*)&P[l15 * 80 + ((G ^ xl) * 8) + ((quad & 1) * 4)] = pk;
        }
        bf16_8 pf0 = *(const bf16_8*)&P[l15 * 80 + ((quad ^ xl) * 8)];
        bf16_8 pf1 = *(const bf16_8*)&P[l15 * 80 + (((quad + 4) ^ xl) * 8)];

        // ---- O^T[d][q] += V^T.P^T ----
#pragma unroll
        for (int dt = 0; dt < 4; dt++) {
            const bf16* vp = &Vs[(dt * 16 + l15) * 64];
            bf16_8 vb0 = *(const bf16_8*)&vp[(quad ^ xl) * 8];
            bf16_8 vb1 = *(const bf16_8*)&vp[((quad + 4) ^ xl) * 8];
            o_acc[dt] = __builtin_amdgcn_mfma_f32_16x16x32_bf16(vb0, pf0, o_acc[dt], 0, 0, 0);
            o_acc[dt] = __builtin_amdgcn_mfma_f32_16x16x32_bf16(vb1, pf1, o_acc[dt], 0, 0, 0);
        }
    }

    l_lane += __shfl_xor(l_lane, 16);
    l_lane += __shfl_xor(l_lane, 32);
    const float rl = 1.0f / l_lane;

    // O^T -> LDS [q][d] -> coalesced b128 stores
#pragma unroll
    for (int dt = 0; dt < 4; dt++) {
        bf16_4 pk;
#pragma unroll
        for (int r = 0; r < 4; r++) pk[r] = (bf16)(o_acc[dt][r] * rl);
        int G = dt * 2 + (quad >> 1);
        *(bf16_4*)&P[l15 * 80 + ((G ^ xl) * 8) + ((quad & 1) * 4)] = pk;
    }
    const int q2 = lane >> 2, dc = lane & 3, x2 = q2 & 7;
    bf16_8 o0 = *(const bf16_8*)&P[q2 * 80 + (((dc * 2) ^ x2) * 8)];
    bf16_8 o1 = *(const bf16_8*)&P[q2 * 80 + (((dc * 2 + 1) ^ x2) * 8)];
    const size_t row = (size_t)b * SEQ + qb * 64 + wave * 16 + q2;
    *(bf16_8*)&O[row * D_MODEL + h * 64 + dc * 16] = o0;
    *(bf16_8*)&O[row * D_MODEL + h * 64 + dc * 16 + 8] = o1;
}

// ---------------- fused residual + 4-way partial add + LayerNorm -----------
template <bool A32, bool O32>
__global__ __launch_bounds__(256)
void ln_kernel(const void* __restrict__ av, const bf16* __restrict__ p0,
               const bf16* __restrict__ p1, const bf16* __restrict__ p2,
               const bf16* __restrict__ p3,
               const float* __restrict__ gamma, const float* __restrict__ beta,
               void* __restrict__ yv) {
    const int row = blockIdx.x;
    const int tid = threadIdx.x;
    const size_t off = (size_t)row * D_MODEL;
    float v[4];
    {
        bf16_4 a0 = *(const bf16_4*)(p0 + off + tid * 4);
        bf16_4 a1 = *(const bf16_4*)(p1 + off + tid * 4);
        bf16_4 a2 = *(const bf16_4*)(p2 + off + tid * 4);
        bf16_4 a3 = *(const bf16_4*)(p3 + off + tid * 4);
        if (A32) {
            float4 xa = *(const float4*)((const float*)av + off + tid * 4);
            v[0] = xa.x; v[1] = xa.y; v[2] = xa.z; v[3] = xa.w;
        } else {
            bf16_4 xa = *(const bf16_4*)((const bf16*)av + off + tid * 4);
#pragma unroll
            for (int i = 0; i < 4; i++) v[i] = (float)xa[i];
        }
#pragma unroll
        for (int i = 0; i < 4; i++)
            v[i] += ((float)a0[i] + (float)a1[i]) + ((float)a2[i] + (float)a3[i]);
    }
    float s = v[0] + v[1] + v[2] + v[3];
    float ss = v[0] * v[0] + v[1] * v[1] + v[2] * v[2] + v[3] * v[3];
#pragma unroll
    for (int m = 1; m < 64; m <<= 1) {
        s  += __shfl_xor(s, m);
        ss += __shfl_xor(ss, m);
    }
    __shared__ float red_s[4], red_q[4];
    int wave = tid >> 6, lane = tid & 63;
    if (lane == 0) { red_s[wave] = s; red_q[wave] = ss; }
    __syncthreads();
    s  = red_s[0] + red_s[1] + red_s[2] + red_s[3];
    ss = red_q[0] + red_q[1] + red_q[2] + red_q[3];
    float mu   = s * (1.f / D_MODEL);
    float var  = ss * (1.f / D_MODEL) - mu * mu;
    float rstd = rsqrtf(var + 1e-5f);
    float4 gg = *(const float4*)(gamma + tid * 4);
    float4 be = *(const float4*)(beta + tid * 4);
    float y0 = (v[0] - mu) * rstd * gg.x + be.x;
    float y1 = (v[1] - mu) * rstd * gg.y + be.y;
    float y2 = (v[2] - mu) * rstd * gg.z + be.z;
    float y3 = (v[3] - mu) * rstd * gg.w + be.w;
    if (O32) {
        *(float4*)((float*)yv + off + tid * 4) = make_float4(y0, y1, y2, y3);
    } else {
        bf16_4 o;
        o[0] = (bf16)y0; o[1] = (bf16)y1; o[2] = (bf16)y2; o[3] = (bf16)y3;
        *(bf16_4*)((bf16*)yv + off + tid * 4) = o;
    }
}

extern "C" void kernel_launch(void* const* d_in, const int* in_sizes, int n_in,
                              void* d_out, int out_size, void* d_ws, size_t ws_size,
                              hipStream_t stream) {
    (void)in_sizes; (void)n_in; (void)out_size; (void)ws_size;
    const float* x  = (const float*)d_in[0];
    const float* Wq = (const float*)d_in[1];
    const float* Wk = (const float*)d_in[2];
    const float* Wv = (const float*)d_in[3];
    const float* Wo = (const float*)d_in[4];
    const float* W1 = (const float*)d_in[5];
    const float* W2 = (const float*)d_in[6];
    const float* g1 = (const float*)d_in[7];
    const float* b1 = (const float*)d_in[8];
    const float* g2 = (const float*)d_in[9];
    const float* b2 = (const float*)d_in[10];

    char* ws = (char*)d_ws;
    // layout (bytes), total 96 MB. Timeline overlays:
    //   xb/aob [0,8M): cast x -> QKV input -> attn out -> dead after Wo
    //   ln1b   [0,8M): written by LN1 (after Wo), read by FF1 + LN2
    //   QKVb [8M,32M) + Vtb [32M,40M): dead after attn -> hb [8M,40M)
    bf16*  xb    = (bf16*)(ws + 0);          // 8 MB
    bf16*  aob   = xb;
    bf16*  ln1b  = (bf16*)(ws + 0);          // 8 MB (after aob dead)
    bf16*  QKVb  = (bf16*)(ws + 8388608);    // 24 MB [4096][3072] (V third unused)
    bf16*  Vtb   = (bf16*)(ws + 33554432);   // 8 MB  [b][1024][2048]
    bf16*  hb    = (bf16*)(ws + 8388608);    // 32 MB (overlay, post-attn)
    bf16*  Wqkvb = (bf16*)(ws + 41943040);   // 6 MB [3072][1024]
    bf16*  Wob   = (bf16*)(ws + 48234496);   // 2 MB
    bf16*  W1b   = (bf16*)(ws + 50331648);   // 8 MB
    bf16*  W2b   = (bf16*)(ws + 58720256);   // 8 MB
    bf16*  proj0 = (bf16*)(ws + 67108864);   // 4 x 8 MB split-K partials
    const size_t PSTRIDE = (size_t)NTOK * D_MODEL;  // 4M elements

    cast_all<<<dim3(16384), 256, 0, stream>>>(x, Wq, Wk, Wv, Wo, W1, W2,
                                              xb, Wqkvb, Wob, W1b, W2b);

    // fused QKV projection; V third stored transposed into Vtb (EPI=3)
    gemm_bt<3><<<dim3(NTOK / 128, 3072 / 128, 1), 256, 0, stream>>>(
        xb, Wqkvb, QKVb, 0, Vtb, NTOK, 3072, D_MODEL, D_MODEL);

    attn3<<<dim3(1024), 256, 0, stream>>>(QKVb, Vtb, aob);

    // Wo projection, split-K=4 (partials summed in LN1)
    gemm_bt<0><<<dim3(NTOK / 128, D_MODEL / 128, 4), 256, 0, stream>>>(
        aob, Wob, proj0, PSTRIDE, nullptr, NTOK, D_MODEL, D_MODEL, 256);
    ln_kernel<true, false><<<NTOK, 256, 0, stream>>>(
        x, proj0, proj0 + PSTRIDE, proj0 + 2 * PSTRIDE, proj0 + 3 * PSTRIDE,
        g1, b1, ln1b);

    // FF1 + exact GELU
    gemm_bt<2><<<dim3(NTOK / 128, D_FF / 128, 1), 256, 0, stream>>>(
        ln1b, W1b, hb, 0, nullptr, NTOK, D_FF, D_MODEL, D_MODEL);

    // FF2, split-K=4 (partials summed in LN2)
    gemm_bt<0><<<dim3(NTOK / 128, D_MODEL / 128, 4), 256, 0, stream>>>(
        hb, W2b, proj0, PSTRIDE, nullptr, NTOK, D_MODEL, D_FF, 1024);
    ln_kernel<false, true><<<NTOK, 256, 0, stream>>>(
        ln1b, proj0, proj0 + PSTRIDE, proj0 + 2 * PSTRIDE, proj0 + 3 * PSTRIDE,
        g2, b2, d_out);
}